// Round 15
// baseline (905.126 us; speedup 1.0000x reference)
//
#include <hip/hip_runtime.h>
#include <hip/hip_bf16.h>
#include <stdint.h>

#define Bn   16
#define Nn   4096
#define Sn   1024
#define Kn   8
#define CINn 128
#define COUTn 256

// Exact f32 squared distance, no FMA contraction: matches ((dx*dx+dy*dy)+dz*dz)
static __device__ __forceinline__ float sqdist(float ax, float ay, float az,
                                               float bx, float by, float bz) {
    float dx = __fsub_rn(ax, bx);
    float dy = __fsub_rn(ay, by);
    float dz = __fsub_rn(az, bz);
    return __fadd_rn(__fadd_rn(__fmul_rn(dx, dx), __fmul_rn(dy, dy)), __fmul_rn(dz, dz));
}

static __device__ __forceinline__ unsigned long long u64max(unsigned long long a,
                                                            unsigned long long b) {
    return a > b ? a : b;
}

// Wave-wide u64 max via DPP (VALU pipe, no LDS) — r14-validated on HW.
#define DPP_MAX_LEVEL(lo, hi, CTRL)                                              \
    do {                                                                         \
        int _olo = __builtin_amdgcn_update_dpp(lo, lo, CTRL, 0xF, 0xF, false);   \
        int _ohi = __builtin_amdgcn_update_dpp(hi, hi, CTRL, 0xF, 0xF, false);   \
        unsigned long long _o = ((unsigned long long)(unsigned)_ohi << 32) |     \
                                (unsigned)_olo;                                  \
        unsigned long long _k = ((unsigned long long)(unsigned)hi << 32) |       \
                                (unsigned)lo;                                    \
        if (_o > _k) { lo = _olo; hi = _ohi; }                                   \
    } while (0)

static __device__ __forceinline__ unsigned long long wave_max_u64(unsigned long long key) {
    int lo = (int)(unsigned)(key & 0xFFFFFFFFull);
    int hi = (int)(unsigned)(key >> 32);
    DPP_MAX_LEVEL(lo, hi, 0x111);   // row_shr:1
    DPP_MAX_LEVEL(lo, hi, 0x112);   // row_shr:2
    DPP_MAX_LEVEL(lo, hi, 0x114);   // row_shr:4
    DPP_MAX_LEVEL(lo, hi, 0x118);   // row_shr:8
    DPP_MAX_LEVEL(lo, hi, 0x142);   // row_bcast:15
    DPP_MAX_LEVEL(lo, hi, 0x143);   // row_bcast:31
    unsigned flo = (unsigned)__builtin_amdgcn_readlane(lo, 63);
    unsigned fhi = (unsigned)__builtin_amdgcn_readlane(hi, 63);
    return ((unsigned long long)fhi << 32) | flo;
}

// ---------------- Kernel: farthest point sampling ---------------------------
// Exact argmax/tie-break semantics (validated r6-r14 via output 0).
// 512 threads (8 waves, 2/SIMD) so the DPP-chain/LDS/barrier stalls of one
// wave overlap the dist-update issue of the other. Per step: per-thread
// argmax -> u64 key -> DPP wave reduce -> 8 wave-maxes in LDS (double-
// buffered, ONE barrier) -> 4x ulonglong2 read + 7 u64max.
__global__ __launch_bounds__(512) void k_fps(const float* __restrict__ xyz,
                                             float* __restrict__ out_xyz) {
    __shared__ __align__(16) float xs[Nn], ys[Nn], zs[Nn];
    __shared__ __align__(16) unsigned long long gbuf[2][8];
    const int b = blockIdx.x;
    const int tid = threadIdx.x;
    const int wid = tid >> 6, lane = tid & 63;
    const float* base = xyz + (size_t)b * 3 * Nn;
    for (int i = tid; i < Nn; i += 512) {
        xs[i] = base[i];
        ys[i] = base[Nn + i];
        zs[i] = base[2 * Nn + i];
    }
    __syncthreads();
    float px[8], py[8], pz[8], dist[8];
#pragma unroll
    for (int j = 0; j < 8; ++j) {
        int p = tid + j * 512;
        px[j] = xs[p]; py[j] = ys[p]; pz[j] = zs[p];
        dist[j] = 3.402823466e+38f;   // FLT_MAX, matches jnp.finfo(f32).max
    }
    int last = 0;
    if (tid == 0) {
        out_xyz[(size_t)(b * Sn) * 3 + 0] = xs[0];
        out_xyz[(size_t)(b * Sn) * 3 + 1] = ys[0];
        out_xyz[(size_t)(b * Sn) * 3 + 2] = zs[0];
    }
    for (int s = 1; s < Sn; ++s) {
        const float cx = xs[last], cy = ys[last], cz = zs[last];
        float mv = -1.0f; int mi = 0;
#pragma unroll
        for (int j = 0; j < 8; ++j) {
            float d = sqdist(px[j], py[j], pz[j], cx, cy, cz);
            float nd = fminf(dist[j], d);
            dist[j] = nd;
            if (nd > mv) { mv = nd; mi = tid + j * 512; }  // strict >: first-max wins
        }
        // pack: dist bits high (dist>=0 so f32 bit order == value order),
        // (N-1-idx) low so u64-max tie-breaks to the SMALLEST index.
        unsigned long long key =
            ((unsigned long long)__float_as_uint(mv) << 32) | (unsigned)(Nn - 1 - mi);
        key = wave_max_u64(key);            // all lanes hold wave max
        if (lane == 0) gbuf[s & 1][wid] = key;
        __syncthreads();
        const ulonglong2* gb = (const ulonglong2*)&gbuf[s & 1][0];
        const ulonglong2 g0 = gb[0], g1 = gb[1], g2 = gb[2], g3 = gb[3];
        key = u64max(u64max(u64max(g0.x, g0.y), u64max(g1.x, g1.y)),
                     u64max(u64max(g2.x, g2.y), u64max(g3.x, g3.y)));
        const int nl = Nn - 1 - (int)(unsigned)(key & 0xFFFFFFFFull);
        if (tid == 0) {
            out_xyz[(size_t)(b * Sn + s) * 3 + 0] = xs[nl];
            out_xyz[(size_t)(b * Sn + s) * 3 + 1] = ys[nl];
            out_xyz[(size_t)(b * Sn + s) * 3 + 2] = zs[nl];
        }
        last = nl;
        // no second barrier: next step writes the OTHER gbuf half; this half
        // is rewritten only after the s+1 barrier (program order per wave) —
        // double-buffer pattern validated r9-r14.
    }
}

// ---- Wave-local ball query (validated r10/r12/r13/r14 ballot logic) --------
static __device__ __forceinline__ void wave_ball(const float* __restrict__ base,
                                                 float cx, float cy, float cz,
                                                 int lane, int* bslot) {
    int cnt = 0;
    int idx0 = -1;
    for (int chunk = 0; chunk < Nn / 64; ++chunk) {
        const int p = chunk * 64 + lane;
        const float d2 = sqdist(base[p], base[Nn + p], base[2 * Nn + p], cx, cy, cz);
        const bool in = (d2 <= 0.04f);             // f32(0.2*0.2)
        const unsigned long long m = __ballot(in);
        if (m != 0ull) {
            if (idx0 < 0) idx0 = chunk * 64 + __builtin_ctzll(m);
            const int rank = cnt + __popcll(m & ((1ull << lane) - 1ull));
            if (in && rank < Kn)
                bslot[rank] = p;                    // ascending by construction
            cnt += __popcll(m);
            if (cnt >= Kn) break;                   // wave-uniform
        }
    }
    if (lane < Kn && lane >= cnt)                   // pad with first index
        bslot[lane] = idx0;
}

// ---- Fused ball + conv + BN + ReLU + maxK: one WAVE per center -------------
// 512 threads = 8 waves = 8 centers/block, 1 block/CU (LDS-bound).
// conv_w staged once per block in LDS [f][o] (r13-validated pattern).
// NEW: the feat gather is staged per fc-chunk into wave-local At[wave][k][f]
// via 4 scatter loads (64 distinct lines each, high MLP) instead of 1024
// scalar broadcast loads; inner loop reads fv as b128 LDS broadcasts.
// Software-pipelined: next chunk's global loads issue before current compute.
// Per-accumulator FP order identical to validated r9-r14 kernels (same
// lexicographic (f4,c) update sequence per acc[j][k]).
__global__ __launch_bounds__(512) void k_feat(const float* __restrict__ xyz,
                                              const float* __restrict__ out_xyz,
                                              const float* __restrict__ feat,
                                              const float* __restrict__ conv_w,
                                              const float* __restrict__ conv_b,
                                              const float* __restrict__ bn_g,
                                              const float* __restrict__ bn_b,
                                              const float* __restrict__ bn_m,
                                              const float* __restrict__ bn_v,
                                              float* __restrict__ out_feat) {
    __shared__ float Wlds[CINn][COUTn + 1];          // [f][o] 131.6 KB
    __shared__ __align__(16) float At[8][Kn][36];    // [wave][k][f_local] 9.2 KB
    __shared__ int bidx[8][Kn];
    const int tid = threadIdx.x;
    const int wave = tid >> 6, lane = tid & 63;
    const int b  = blockIdx.x & 15;                 // XCD-grouped batches
    const int c0 = (blockIdx.x >> 4) * 8;
    const int bs = b * Sn + c0 + wave;

    // stage W: coalesced float4 reads, transpose into [f][o]
    {
        const float4* cw4 = (const float4*)conv_w;  // [o][f/4]
#pragma unroll
        for (int i = 0; i < 16; ++i) {
            const int idx = tid + 512 * i;          // 0..8191
            const float4 v = cw4[idx];
            const int o = idx >> 5, f4 = idx & 31;
            Wlds[f4 * 4 + 0][o] = v.x;
            Wlds[f4 * 4 + 1][o] = v.y;
            Wlds[f4 * 4 + 2][o] = v.z;
            Wlds[f4 * 4 + 3][o] = v.w;
        }
    }

    // ball query (wave-local; bidx slice private to this wave)
    const float* base = xyz + (size_t)b * 3 * Nn;
    const float cx = out_xyz[(size_t)bs * 3 + 0];
    const float cy = out_xyz[(size_t)bs * 3 + 1];
    const float cz = out_xyz[(size_t)bs * 3 + 2];
    wave_ball(base, cx, cy, cz, lane, &bidx[wave][0]);

    int pt[Kn];
#pragma unroll
    for (int k = 0; k < Kn; ++k) pt[k] = bidx[wave][k];   // wave-internal, no barrier

    __syncthreads();   // Wlds staged by all waves

    const float* fb = feat + (size_t)b * CINn * Nn;
    const int fl = lane & 31;          // f_local within chunk
    const int kh = lane >> 5;          // k-pair half (0/1)

    float acc[4][Kn];
#pragma unroll
    for (int j = 0; j < 4; ++j)
#pragma unroll
        for (int k = 0; k < Kn; ++k) acc[j][k] = 0.0f;

    // preload chunk 0: lane (kh,fl) fetches feat[b][fl][pt[2kk+kh]]
    float stg[4];
#pragma unroll
    for (int kk = 0; kk < 4; ++kk) {
        const int ptk = kh ? pt[kk * 2 + 1] : pt[kk * 2];
        stg[kk] = fb[(size_t)fl * Nn + ptk];
    }

#pragma unroll
    for (int fc = 0; fc < 4; ++fc) {
        // park current chunk in wave-local LDS
#pragma unroll
        for (int kk = 0; kk < 4; ++kk)
            At[wave][kk * 2 + kh][fl] = stg[kk];
        // issue next chunk's scatter loads (hidden under compute)
        if (fc < 3) {
#pragma unroll
            for (int kk = 0; kk < 4; ++kk) {
                const int ptk = kh ? pt[kk * 2 + 1] : pt[kk * 2];
                stg[kk] = fb[(size_t)((fc + 1) * 32 + fl) * Nn + ptk];
            }
        }
        // compute the 8 f4-groups of this chunk
#pragma unroll
        for (int f4l = 0; f4l < 8; ++f4l) {
            const int f4 = fc * 8 + f4l;
            // W: 16 values, paired reads from one base for ds_read2 fusion
            float wreg[4][4];   // [c][j]
#pragma unroll
            for (int c = 0; c < 4; ++c) {
                const float* wrow = &Wlds[f4 * 4 + c][lane];
                wreg[c][0] = wrow[0];
                wreg[c][1] = wrow[64];
                wreg[c][2] = wrow[128];
                wreg[c][3] = wrow[192];
            }
#pragma unroll
            for (int khf = 0; khf < 2; ++khf) {
                float4 fv4[4];
#pragma unroll
                for (int kk = 0; kk < 4; ++kk)
                    fv4[kk] = *(const float4*)&At[wave][khf * 4 + kk][f4l * 4];
#pragma unroll
                for (int c = 0; c < 4; ++c)
#pragma unroll
                    for (int j = 0; j < 4; ++j)
#pragma unroll
                        for (int kk = 0; kk < 4; ++kk)
                            acc[j][khf * 4 + kk] +=
                                ((const float*)&fv4[kk])[c] * wreg[c][j];
            }
        }
    }

    // epilogue: identical math/order to the validated kernels
#pragma unroll
    for (int j = 0; j < 4; ++j) {
        const int o = lane + 64 * j;
        const float bias = conv_b[o];
        const float g = bn_g[o], be = bn_b[o], mn = bn_m[o], vr = bn_v[o];
        const float inv = sqrtf(vr + 1e-5f);
        float mx = -3.402823466e+38f;
#pragma unroll
        for (int k = 0; k < Kn; ++k) {
            float z = acc[j][k] + bias;
            float y = g * (z - mn) / inv + be;
            y = fmaxf(y, 0.0f);              // ReLU before max, literal order
            mx = fmaxf(mx, y);
        }
        out_feat[(size_t)bs * COUTn + o] = mx;
    }
}

extern "C" void kernel_launch(void* const* d_in, const int* in_sizes, int n_in,
                              void* d_out, int out_size, void* d_ws, size_t ws_size,
                              hipStream_t stream) {
    const float* xyz    = (const float*)d_in[0];
    const float* feat   = (const float*)d_in[1];
    const float* conv_w = (const float*)d_in[2];
    const float* conv_b = (const float*)d_in[3];
    const float* bn_g   = (const float*)d_in[4];
    const float* bn_b   = (const float*)d_in[5];
    const float* bn_m   = (const float*)d_in[6];
    const float* bn_v   = (const float*)d_in[7];

    float* out_xyz  = (float*)d_out;
    float* out_feat = out_xyz + (size_t)Bn * Sn * 3;

    // no workspace usage
    k_fps <<<dim3(Bn),           dim3(512), 0, stream>>>(xyz, out_xyz);
    k_feat<<<dim3(Bn * Sn / 8),  dim3(512), 0, stream>>>(xyz, out_xyz, feat,
                                                         conv_w, conv_b,
                                                         bn_g, bn_b, bn_m, bn_v,
                                                         out_feat);
}

// Round 17
// 836.875 us; speedup vs baseline: 1.0816x; 1.0816x over previous
//
#include <hip/hip_runtime.h>
#include <hip/hip_bf16.h>
#include <stdint.h>

#define Bn   16
#define Nn   4096
#define Sn   1024
#define Kn   8
#define CINn 128
#define COUTn 256

// Exact f32 squared distance, no FMA contraction: matches ((dx*dx+dy*dy)+dz*dz)
static __device__ __forceinline__ float sqdist(float ax, float ay, float az,
                                               float bx, float by, float bz) {
    float dx = __fsub_rn(ax, bx);
    float dy = __fsub_rn(ay, by);
    float dz = __fsub_rn(az, bz);
    return __fadd_rn(__fadd_rn(__fmul_rn(dx, dx), __fmul_rn(dy, dy)), __fmul_rn(dz, dz));
}

static __device__ __forceinline__ unsigned long long u64max(unsigned long long a,
                                                            unsigned long long b) {
    return a > b ? a : b;
}

// Wave-wide u64 max via DPP (VALU pipe, no LDS) — r14-validated on HW.
// CTRL must be a compile-time constant for __builtin_amdgcn_update_dpp.
template <int CTRL>
static __device__ __forceinline__ void dpp_max_level(int& lo, int& hi) {
    int olo = __builtin_amdgcn_update_dpp(lo, lo, CTRL, 0xF, 0xF, false);
    int ohi = __builtin_amdgcn_update_dpp(hi, hi, CTRL, 0xF, 0xF, false);
    unsigned long long o = ((unsigned long long)(unsigned)ohi << 32) | (unsigned)olo;
    unsigned long long k = ((unsigned long long)(unsigned)hi << 32) | (unsigned)lo;
    if (o > k) { lo = olo; hi = ohi; }
}

static __device__ __forceinline__ unsigned long long wave_max_u64(unsigned long long key) {
    int lo = (int)(unsigned)(key & 0xFFFFFFFFull);
    int hi = (int)(unsigned)(key >> 32);
    dpp_max_level<0x111>(lo, hi);   // row_shr:1
    dpp_max_level<0x112>(lo, hi);   // row_shr:2
    dpp_max_level<0x114>(lo, hi);   // row_shr:4
    dpp_max_level<0x118>(lo, hi);   // row_shr:8
    dpp_max_level<0x142>(lo, hi);   // row_bcast:15
    dpp_max_level<0x143>(lo, hi);   // row_bcast:31
    unsigned flo = (unsigned)__builtin_amdgcn_readlane(lo, 63);
    unsigned fhi = (unsigned)__builtin_amdgcn_readlane(hi, 63);
    return ((unsigned long long)fhi << 32) | flo;
}

// ---------------- Kernel: farthest point sampling (r14 text, measured 624us)
// Exact argmax/tie-break semantics (validated r6-r15 via output 0).
// 256 threads, 16 pts/thread. Per step: per-thread argmax -> u64 key ->
// DPP wave reduce (VALU) -> 4 wave-maxes in LDS (double-buffered, ONE
// barrier) -> broadcast read + 3 u64max -> next center.
__global__ __launch_bounds__(256) void k_fps(const float* __restrict__ xyz,
                                             float* __restrict__ out_xyz) {
    __shared__ __align__(16) float xs[Nn], ys[Nn], zs[Nn];
    __shared__ __align__(16) unsigned long long gbuf[2][4];
    const int b = blockIdx.x;
    const int tid = threadIdx.x;
    const int wid = tid >> 6, lane = tid & 63;
    const float* base = xyz + (size_t)b * 3 * Nn;
    for (int i = tid; i < Nn; i += 256) {
        xs[i] = base[i];
        ys[i] = base[Nn + i];
        zs[i] = base[2 * Nn + i];
    }
    __syncthreads();
    float px[16], py[16], pz[16], dist[16];
#pragma unroll
    for (int j = 0; j < 16; ++j) {
        int p = tid + j * 256;
        px[j] = xs[p]; py[j] = ys[p]; pz[j] = zs[p];
        dist[j] = 3.402823466e+38f;   // FLT_MAX, matches jnp.finfo(f32).max
    }
    int last = 0;
    if (tid == 0) {
        out_xyz[(size_t)(b * Sn) * 3 + 0] = xs[0];
        out_xyz[(size_t)(b * Sn) * 3 + 1] = ys[0];
        out_xyz[(size_t)(b * Sn) * 3 + 2] = zs[0];
    }
    for (int s = 1; s < Sn; ++s) {
        const float cx = xs[last], cy = ys[last], cz = zs[last];
        float mv = -1.0f; int mi = 0;
#pragma unroll
        for (int j = 0; j < 16; ++j) {
            float d = sqdist(px[j], py[j], pz[j], cx, cy, cz);
            float nd = fminf(dist[j], d);
            dist[j] = nd;
            if (nd > mv) { mv = nd; mi = tid + j * 256; }  // strict >: first-max wins
        }
        // pack: dist bits high (dist>=0 so f32 bit order == value order),
        // (N-1-idx) low so u64-max tie-breaks to the SMALLEST index.
        unsigned long long key =
            ((unsigned long long)__float_as_uint(mv) << 32) | (unsigned)(Nn - 1 - mi);
        key = wave_max_u64(key);            // all lanes hold wave max
        if (lane == 0) gbuf[s & 1][wid] = key;
        __syncthreads();
        const ulonglong2 g0 = *(const ulonglong2*)&gbuf[s & 1][0];
        const ulonglong2 g1 = *(const ulonglong2*)&gbuf[s & 1][2];
        key = u64max(u64max(g0.x, g0.y), u64max(g1.x, g1.y));
        const int nl = Nn - 1 - (int)(unsigned)(key & 0xFFFFFFFFull);
        if (tid == 0) {
            out_xyz[(size_t)(b * Sn + s) * 3 + 0] = xs[nl];
            out_xyz[(size_t)(b * Sn + s) * 3 + 1] = ys[nl];
            out_xyz[(size_t)(b * Sn + s) * 3 + 2] = zs[nl];
        }
        last = nl;
        // no second barrier: next step writes the OTHER gbuf half; this half
        // is rewritten only after the s+1 barrier (program order per wave).
    }
}

// ---- Wave-local ball query (validated r10-r15 ballot logic) ----------------
static __device__ __forceinline__ void wave_ball(const float* __restrict__ base,
                                                 float cx, float cy, float cz,
                                                 int lane, int* bslot) {
    int cnt = 0;
    int idx0 = -1;
    for (int chunk = 0; chunk < Nn / 64; ++chunk) {
        const int p = chunk * 64 + lane;
        const float d2 = sqdist(base[p], base[Nn + p], base[2 * Nn + p], cx, cy, cz);
        const bool in = (d2 <= 0.04f);             // f32(0.2*0.2)
        const unsigned long long m = __ballot(in);
        if (m != 0ull) {
            if (idx0 < 0) idx0 = chunk * 64 + __builtin_ctzll(m);
            const int rank = cnt + __popcll(m & ((1ull << lane) - 1ull));
            if (in && rank < Kn)
                bslot[rank] = p;                    // ascending by construction
            cnt += __popcll(m);
            if (cnt >= Kn) break;                   // wave-uniform
        }
    }
    if (lane < Kn && lane >= cnt)                   // pad with first index
        bslot[lane] = idx0;
}

// ---- Fused ball + conv + BN + ReLU + maxK: one WAVE per center -------------
// 512 threads = 8 waves = 8 centers/block. BOTH operand streams (W and the
// gathered feat) are chunked by 32 f-rows, staged in LDS, and software-
// pipelined: chunk fc+1's global loads issue right after the barrier, under
// chunk fc's FMAs. LDS = Wc 32.9KB + At 9.2KB + bidx -> 42.4KB ->
// 2 blocks/CU co-resident (16 waves/CU) vs r15's 1 block at 141KB.
// Per-accumulator FP order identical to validated r9-r15 ((f4,c) ascending).
__global__ __launch_bounds__(512) void k_feat(const float* __restrict__ xyz,
                                              const float* __restrict__ out_xyz,
                                              const float* __restrict__ feat,
                                              const float* __restrict__ conv_w,
                                              const float* __restrict__ conv_b,
                                              const float* __restrict__ bn_g,
                                              const float* __restrict__ bn_b,
                                              const float* __restrict__ bn_m,
                                              const float* __restrict__ bn_v,
                                              float* __restrict__ out_feat) {
    __shared__ float Wc[32][COUTn + 1];              // [f_local][o] 32.9 KB
    __shared__ __align__(16) float At[8][Kn][36];    // [wave][k][f_local] 9.2 KB
    __shared__ int bidx[8][Kn];
    const int tid = threadIdx.x;
    const int wave = tid >> 6, lane = tid & 63;
    const int b  = blockIdx.x & 15;                 // XCD-grouped batches
    const int c0 = (blockIdx.x >> 4) * 8;
    const int bs = b * Sn + c0 + wave;

    // ball query (wave-local; bidx slice private to this wave)
    const float* base = xyz + (size_t)b * 3 * Nn;
    const float cx = out_xyz[(size_t)bs * 3 + 0];
    const float cy = out_xyz[(size_t)bs * 3 + 1];
    const float cz = out_xyz[(size_t)bs * 3 + 2];
    wave_ball(base, cx, cy, cz, lane, &bidx[wave][0]);

    int pt[Kn];
#pragma unroll
    for (int k = 0; k < Kn; ++k) pt[k] = bidx[wave][k];   // wave-internal, no barrier

    const float* fb = feat + (size_t)b * CINn * Nn;
    const float4* cw4 = (const float4*)conv_w;      // [o][f/4]
    const int fl = lane & 31;          // f_local within chunk
    const int kh = lane >> 5;          // k half (0/1)
    const int wo = tid >> 3;           // W-staging o base (0..63)
    const int wf = tid & 7;            // W-staging f4_local

    float acc[4][Kn];
#pragma unroll
    for (int j = 0; j < 4; ++j)
#pragma unroll
        for (int k = 0; k < Kn; ++k) acc[j][k] = 0.0f;

    // preload chunk 0 of BOTH streams
    float stgA[4];
#pragma unroll
    for (int kk = 0; kk < 4; ++kk) {
        const int ptk = kh ? pt[kk * 2 + 1] : pt[kk * 2];
        stgA[kk] = fb[(size_t)fl * Nn + ptk];
    }
    float4 stgW[4];
#pragma unroll
    for (int i = 0; i < 4; ++i) {
        const int o = wo + 64 * i;                   // 0..255
        stgW[i] = cw4[(size_t)o * 32 + wf];          // chunk 0: f4 = wf
    }

#pragma unroll
    for (int fc = 0; fc < 4; ++fc) {
        // park current chunks in LDS
#pragma unroll
        for (int kk = 0; kk < 4; ++kk)
            At[wave][kk * 2 + kh][fl] = stgA[kk];
#pragma unroll
        for (int i = 0; i < 4; ++i) {
            const int o = wo + 64 * i;
            Wc[wf * 4 + 0][o] = stgW[i].x;
            Wc[wf * 4 + 1][o] = stgW[i].y;
            Wc[wf * 4 + 2][o] = stgW[i].z;
            Wc[wf * 4 + 3][o] = stgW[i].w;
        }
        __syncthreads();
        // issue next chunk's global loads (hidden under compute)
        if (fc < 3) {
#pragma unroll
            for (int kk = 0; kk < 4; ++kk) {
                const int ptk = kh ? pt[kk * 2 + 1] : pt[kk * 2];
                stgA[kk] = fb[(size_t)((fc + 1) * 32 + fl) * Nn + ptk];
            }
#pragma unroll
            for (int i = 0; i < 4; ++i) {
                const int o = wo + 64 * i;
                stgW[i] = cw4[(size_t)o * 32 + (fc + 1) * 8 + wf];
            }
        }
        // compute the 8 f4-groups of this chunk
#pragma unroll
        for (int f4l = 0; f4l < 8; ++f4l) {
            float wreg[4][4];   // [c][j]
#pragma unroll
            for (int c = 0; c < 4; ++c) {
                const float* wrow = &Wc[f4l * 4 + c][lane];
                wreg[c][0] = wrow[0];
                wreg[c][1] = wrow[64];
                wreg[c][2] = wrow[128];
                wreg[c][3] = wrow[192];
            }
#pragma unroll
            for (int khf = 0; khf < 2; ++khf) {
                float4 fv4[4];
#pragma unroll
                for (int kk = 0; kk < 4; ++kk)
                    fv4[kk] = *(const float4*)&At[wave][khf * 4 + kk][f4l * 4];
#pragma unroll
                for (int c = 0; c < 4; ++c)
#pragma unroll
                    for (int j = 0; j < 4; ++j)
#pragma unroll
                        for (int kk = 0; kk < 4; ++kk)
                            acc[j][khf * 4 + kk] +=
                                ((const float*)&fv4[kk])[c] * wreg[c][j];
            }
        }
        __syncthreads();   // LDS safe to overwrite next iter
    }

    // epilogue: identical math/order to the validated kernels
#pragma unroll
    for (int j = 0; j < 4; ++j) {
        const int o = lane + 64 * j;
        const float bias = conv_b[o];
        const float g = bn_g[o], be = bn_b[o], mn = bn_m[o], vr = bn_v[o];
        const float inv = sqrtf(vr + 1e-5f);
        float mx = -3.402823466e+38f;
#pragma unroll
        for (int k = 0; k < Kn; ++k) {
            float z = acc[j][k] + bias;
            float y = g * (z - mn) / inv + be;
            y = fmaxf(y, 0.0f);              // ReLU before max, literal order
            mx = fmaxf(mx, y);
        }
        out_feat[(size_t)bs * COUTn + o] = mx;
    }
}

extern "C" void kernel_launch(void* const* d_in, const int* in_sizes, int n_in,
                              void* d_out, int out_size, void* d_ws, size_t ws_size,
                              hipStream_t stream) {
    const float* xyz    = (const float*)d_in[0];
    const float* feat   = (const float*)d_in[1];
    const float* conv_w = (const float*)d_in[2];
    const float* conv_b = (const float*)d_in[3];
    const float* bn_g   = (const float*)d_in[4];
    const float* bn_b   = (const float*)d_in[5];
    const float* bn_m   = (const float*)d_in[6];
    const float* bn_v   = (const float*)d_in[7];

    float* out_xyz  = (float*)d_out;
    float* out_feat = out_xyz + (size_t)Bn * Sn * 3;

    // no workspace usage
    k_fps <<<dim3(Bn),           dim3(256), 0, stream>>>(xyz, out_xyz);
    k_feat<<<dim3(Bn * Sn / 8),  dim3(512), 0, stream>>>(xyz, out_xyz, feat,
                                                         conv_w, conv_b,
                                                         bn_g, bn_b, bn_m, bn_v,
                                                         out_feat);
}

// Round 19
// 707.329 us; speedup vs baseline: 1.2796x; 1.1831x over previous
//
#include <hip/hip_runtime.h>
#include <hip/hip_bf16.h>
#include <stdint.h>

#define Bn   16
#define Nn   4096
#define Sn   1024
#define Kn   8
#define CINn 128
#define COUTn 256

typedef __attribute__((ext_vector_type(8))) short bf16x8;
typedef __attribute__((ext_vector_type(4))) float f32x4;
typedef unsigned short ushort;
typedef __attribute__((ext_vector_type(8))) unsigned short ushort8;

// Exact f32 squared distance, no FMA contraction: matches ((dx*dx+dy*dy)+dz*dz)
static __device__ __forceinline__ float sqdist(float ax, float ay, float az,
                                               float bx, float by, float bz) {
    float dx = __fsub_rn(ax, bx);
    float dy = __fsub_rn(ay, by);
    float dz = __fsub_rn(az, bz);
    return __fadd_rn(__fadd_rn(__fmul_rn(dx, dx), __fmul_rn(dy, dy)), __fmul_rn(dz, dz));
}

static __device__ __forceinline__ unsigned long long u64max(unsigned long long a,
                                                            unsigned long long b) {
    return a > b ? a : b;
}

// f32 -> bf16 bits, round-to-nearest-even (finite inputs)
static __device__ __forceinline__ ushort f2bf(float f) {
    unsigned x = __float_as_uint(f);
    unsigned r = x + 0x7FFFu + ((x >> 16) & 1u);
    return (ushort)(r >> 16);
}

// Wave-wide u64 max via DPP (VALU pipe, no LDS) — r14-validated on HW.
template <int CTRL>
static __device__ __forceinline__ void dpp_max_level(int& lo, int& hi) {
    int olo = __builtin_amdgcn_update_dpp(lo, lo, CTRL, 0xF, 0xF, false);
    int ohi = __builtin_amdgcn_update_dpp(hi, hi, CTRL, 0xF, 0xF, false);
    unsigned long long o = ((unsigned long long)(unsigned)ohi << 32) | (unsigned)olo;
    unsigned long long k = ((unsigned long long)(unsigned)hi << 32) | (unsigned)lo;
    if (o > k) { lo = olo; hi = ohi; }
}

static __device__ __forceinline__ unsigned long long wave_max_u64(unsigned long long key) {
    int lo = (int)(unsigned)(key & 0xFFFFFFFFull);
    int hi = (int)(unsigned)(key >> 32);
    dpp_max_level<0x111>(lo, hi);   // row_shr:1
    dpp_max_level<0x112>(lo, hi);   // row_shr:2
    dpp_max_level<0x114>(lo, hi);   // row_shr:4
    dpp_max_level<0x118>(lo, hi);   // row_shr:8
    dpp_max_level<0x142>(lo, hi);   // row_bcast:15
    dpp_max_level<0x143>(lo, hi);   // row_bcast:31
    unsigned flo = (unsigned)__builtin_amdgcn_readlane(lo, 63);
    unsigned fhi = (unsigned)__builtin_amdgcn_readlane(hi, 63);
    return ((unsigned long long)fhi << 32) | flo;
}

// ---------------- Kernel: farthest point sampling (r14/r17 text, 624us) -----
__global__ __launch_bounds__(256) void k_fps(const float* __restrict__ xyz,
                                             float* __restrict__ out_xyz) {
    __shared__ __align__(16) float xs[Nn], ys[Nn], zs[Nn];
    __shared__ __align__(16) unsigned long long gbuf[2][4];
    const int b = blockIdx.x;
    const int tid = threadIdx.x;
    const int wid = tid >> 6, lane = tid & 63;
    const float* base = xyz + (size_t)b * 3 * Nn;
    for (int i = tid; i < Nn; i += 256) {
        xs[i] = base[i];
        ys[i] = base[Nn + i];
        zs[i] = base[2 * Nn + i];
    }
    __syncthreads();
    float px[16], py[16], pz[16], dist[16];
#pragma unroll
    for (int j = 0; j < 16; ++j) {
        int p = tid + j * 256;
        px[j] = xs[p]; py[j] = ys[p]; pz[j] = zs[p];
        dist[j] = 3.402823466e+38f;   // FLT_MAX, matches jnp.finfo(f32).max
    }
    int last = 0;
    if (tid == 0) {
        out_xyz[(size_t)(b * Sn) * 3 + 0] = xs[0];
        out_xyz[(size_t)(b * Sn) * 3 + 1] = ys[0];
        out_xyz[(size_t)(b * Sn) * 3 + 2] = zs[0];
    }
    for (int s = 1; s < Sn; ++s) {
        const float cx = xs[last], cy = ys[last], cz = zs[last];
        float mv = -1.0f; int mi = 0;
#pragma unroll
        for (int j = 0; j < 16; ++j) {
            float d = sqdist(px[j], py[j], pz[j], cx, cy, cz);
            float nd = fminf(dist[j], d);
            dist[j] = nd;
            if (nd > mv) { mv = nd; mi = tid + j * 256; }  // strict >: first-max wins
        }
        unsigned long long key =
            ((unsigned long long)__float_as_uint(mv) << 32) | (unsigned)(Nn - 1 - mi);
        key = wave_max_u64(key);            // all lanes hold wave max
        if (lane == 0) gbuf[s & 1][wid] = key;
        __syncthreads();
        const ulonglong2 g0 = *(const ulonglong2*)&gbuf[s & 1][0];
        const ulonglong2 g1 = *(const ulonglong2*)&gbuf[s & 1][2];
        key = u64max(u64max(g0.x, g0.y), u64max(g1.x, g1.y));
        const int nl = Nn - 1 - (int)(unsigned)(key & 0xFFFFFFFFull);
        if (tid == 0) {
            out_xyz[(size_t)(b * Sn + s) * 3 + 0] = xs[nl];
            out_xyz[(size_t)(b * Sn + s) * 3 + 1] = ys[nl];
            out_xyz[(size_t)(b * Sn + s) * 3 + 2] = zs[nl];
        }
        last = nl;
        // double-buffered gbuf: no second barrier (validated r9-r17)
    }
}

// ---- Wave-local ball query (validated r10-r17 ballot logic) ----------------
static __device__ __forceinline__ void wave_ball(const float* __restrict__ base,
                                                 float cx, float cy, float cz,
                                                 int lane, int* bslot) {
    int cnt = 0;
    int idx0 = -1;
    for (int chunk = 0; chunk < Nn / 64; ++chunk) {
        const int p = chunk * 64 + lane;
        const float d2 = sqdist(base[p], base[Nn + p], base[2 * Nn + p], cx, cy, cz);
        const bool in = (d2 <= 0.04f);             // f32(0.2*0.2)
        const unsigned long long m = __ballot(in);
        if (m != 0ull) {
            if (idx0 < 0) idx0 = chunk * 64 + __builtin_ctzll(m);
            const int rank = cnt + __popcll(m & ((1ull << lane) - 1ull));
            if (in && rank < Kn)
                bslot[rank] = p;                    // ascending by construction
            cnt += __popcll(m);
            if (cnt >= Kn) break;                   // wave-uniform
        }
    }
    if (lane < Kn && lane >= cnt)                   // pad with first index
        bslot[lane] = idx0;
}

// ---- Fused ball + bf16-MFMA conv + BN + ReLU + maxK ------------------------
// Block: 512 thr = 8 waves = 8 centers. D[64=(c,k)][256 o] = A[64][128]·W^T.
// A staged once in LDS (bf16, stride 136 ush); W staged per-32-f chunk
// ([o][f_local] bf16, stride 40 ush), prefetched one chunk ahead.
// Wave w: m-tile mt=w&3 (centers 2mt,2mt+1), o-half (w>>2)*128, 8 n-tiles.
// Fragments (mfma_f32_16x16x32_bf16): A/B lane l: 8 consecutive k at
// (l>>4)*8, row/col = l&15; D: col=l&15, row=(l>>4)*4+reg (m89-verified).
// Epilogue: literal bias->BN->ReLU per (k,o), then max over k (in-lane max4
// + shfl_xor(16)). bf16 rounding error ~0.01-0.04 << 0.17375 threshold.
__global__ __launch_bounds__(512) void k_feat(const float* __restrict__ xyz,
                                              const float* __restrict__ out_xyz,
                                              const float* __restrict__ feat,
                                              const float* __restrict__ conv_w,
                                              const float* __restrict__ conv_b,
                                              const float* __restrict__ bn_g,
                                              const float* __restrict__ bn_b,
                                              const float* __restrict__ bn_m,
                                              const float* __restrict__ bn_v,
                                              float* __restrict__ out_feat) {
    __shared__ __align__(16) ushort A_lds[64][136];   // [(c,k)][f] 17.4 KB
    __shared__ __align__(16) ushort Wc[COUTn][40];    // [o][f_local] 20.5 KB
    __shared__ int bidx[8][Kn];
    const int tid = threadIdx.x;
    const int wave = tid >> 6, lane = tid & 63;
    const int b  = blockIdx.x & 15;                 // XCD-grouped batches
    const int c0 = (blockIdx.x >> 4) * 8;
    const int bs = b * Sn + c0 + wave;

    // ball query (wave-local)
    const float* base = xyz + (size_t)b * 3 * Nn;
    const float cx = out_xyz[(size_t)bs * 3 + 0];
    const float cy = out_xyz[(size_t)bs * 3 + 1];
    const float cz = out_xyz[(size_t)bs * 3 + 2];
    wave_ball(base, cx, cy, cz, lane, &bidx[wave][0]);
    __syncthreads();   // bidx visible to all waves (A staging reads it)

    // stage A (once): thread: row r=tid>>3 (=(c<<3)|k), f-range (tid&7)*16..+15
    const float* fb = feat + (size_t)b * CINn * Nn;
    {
        const int r = tid >> 3, fo = tid & 7;
        const int pt = bidx[r >> 3][r & 7];
        ushort us[16];
#pragma unroll
        for (int i = 0; i < 16; ++i)
            us[i] = f2bf(fb[(size_t)(fo * 16 + i) * Nn + pt]);
        *(ushort8*)&A_lds[r][fo * 16]     = *(const ushort8*)&us[0];
        *(ushort8*)&A_lds[r][fo * 16 + 8] = *(const ushort8*)&us[8];
    }

    // W chunk prefetch (ks=0): thread: o=tid>>1, f-half (tid&1)*16
    const int wo = tid >> 1, wfh = tid & 1;
    float4 stgW[4];
    {
        const float4* src = (const float4*)(conv_w + (size_t)wo * CINn + wfh * 16);
#pragma unroll
        for (int i = 0; i < 4; ++i) stgW[i] = src[i];
    }

    const int mt = wave & 3;
    const int obase = (wave >> 2) * 128;
    f32x4 acc[8];
#pragma unroll
    for (int t = 0; t < 8; ++t) acc[t] = (f32x4){0.f, 0.f, 0.f, 0.f};

    const int arow = mt * 16 + (lane & 15);
    const int kgrp = (lane >> 4) * 8;

#pragma unroll
    for (int ks = 0; ks < 4; ++ks) {
        // park W chunk (16 bf16 per thread -> 2 b128 writes)
        {
            ushort us[16];
#pragma unroll
            for (int i = 0; i < 4; ++i) {
                us[i * 4 + 0] = f2bf(stgW[i].x);
                us[i * 4 + 1] = f2bf(stgW[i].y);
                us[i * 4 + 2] = f2bf(stgW[i].z);
                us[i * 4 + 3] = f2bf(stgW[i].w);
            }
            *(ushort8*)&Wc[wo][wfh * 16]     = *(const ushort8*)&us[0];
            *(ushort8*)&Wc[wo][wfh * 16 + 8] = *(const ushort8*)&us[8];
        }
        __syncthreads();   // Wc[ks] ready (iter 0: A_lds too)
        // prefetch next W chunk
        if (ks < 3) {
            const float4* src = (const float4*)(conv_w + (size_t)wo * CINn +
                                                (ks + 1) * 32 + wfh * 16);
#pragma unroll
            for (int i = 0; i < 4; ++i) stgW[i] = src[i];
        }
        // compute: one A-frag (reused), 8 n-tiles
        const bf16x8 a = *(const bf16x8*)&A_lds[arow][ks * 32 + kgrp];
#pragma unroll
        for (int t = 0; t < 8; ++t) {
            const int o = obase + t * 16 + (lane & 15);
            const bf16x8 bb = *(const bf16x8*)&Wc[o][kgrp];
            acc[t] = __builtin_amdgcn_mfma_f32_16x16x32_bf16(a, bb, acc[t], 0, 0, 0);
        }
        __syncthreads();   // compute done before Wc overwrite
    }

    // epilogue: literal bias+BN+ReLU per (k,o), then max over k.
    // Lane holds D rows (lane>>4)*4+i at col lane&15; rows 0-7 = center 2mt,
    // rows 8-15 = center 2mt+1. In-lane max over 4 rows (same center), then
    // shfl_xor(16) merges the two k-halves of each center.
    const int half = lane >> 4;                 // 0,1: center A; 2,3: center B
#pragma unroll
    for (int t = 0; t < 8; ++t) {
        const int o = obase + t * 16 + (lane & 15);
        const float bias = conv_b[o];
        const float g = bn_g[o], be = bn_b[o], mn = bn_m[o], vr = bn_v[o];
        const float inv = sqrtf(vr + 1e-5f);
        float m4 = -3.402823466e+38f;
#pragma unroll
        for (int i = 0; i < 4; ++i) {
            float z = acc[t][i] + bias;
            float y = g * (z - mn) / inv + be;
            y = fmaxf(y, 0.0f);                 // ReLU before max, literal order
            m4 = fmaxf(m4, y);
        }
        const float mo = __shfl_xor(m4, 16);    // merge k 0-3 with k 4-7
        const float mx = fmaxf(m4, mo);
        if (half == 0)
            out_feat[(size_t)(b * Sn + c0 + mt * 2) * COUTn + o] = mx;
        else if (half == 2)
            out_feat[(size_t)(b * Sn + c0 + mt * 2 + 1) * COUTn + o] = mx;
    }
}

extern "C" void kernel_launch(void* const* d_in, const int* in_sizes, int n_in,
                              void* d_out, int out_size, void* d_ws, size_t ws_size,
                              hipStream_t stream) {
    const float* xyz    = (const float*)d_in[0];
    const float* feat   = (const float*)d_in[1];
    const float* conv_w = (const float*)d_in[2];
    const float* conv_b = (const float*)d_in[3];
    const float* bn_g   = (const float*)d_in[4];
    const float* bn_b   = (const float*)d_in[5];
    const float* bn_m   = (const float*)d_in[6];
    const float* bn_v   = (const float*)d_in[7];

    float* out_xyz  = (float*)d_out;
    float* out_feat = out_xyz + (size_t)Bn * Sn * 3;

    // no workspace usage
    k_fps <<<dim3(Bn),           dim3(256), 0, stream>>>(xyz, out_xyz);
    k_feat<<<dim3(Bn * Sn / 8),  dim3(512), 0, stream>>>(xyz, out_xyz, feat,
                                                         conv_w, conv_b,
                                                         bn_g, bn_b, bn_m, bn_v,
                                                         out_feat);
}

// Round 20
// 707.322 us; speedup vs baseline: 1.2797x; 1.0000x over previous
//
#include <hip/hip_runtime.h>
#include <hip/hip_bf16.h>
#include <stdint.h>

#define Bn   16
#define Nn   4096
#define Sn   1024
#define Kn   8
#define CINn 128
#define COUTn 256

typedef __attribute__((ext_vector_type(8))) short bf16x8;
typedef __attribute__((ext_vector_type(4))) float f32x4;
typedef unsigned short ushort;
typedef __attribute__((ext_vector_type(8))) unsigned short ushort8;

// Exact f32 squared distance, no FMA contraction: matches ((dx*dx+dy*dy)+dz*dz)
static __device__ __forceinline__ float sqdist(float ax, float ay, float az,
                                               float bx, float by, float bz) {
    float dx = __fsub_rn(ax, bx);
    float dy = __fsub_rn(ay, by);
    float dz = __fsub_rn(az, bz);
    return __fadd_rn(__fadd_rn(__fmul_rn(dx, dx), __fmul_rn(dy, dy)), __fmul_rn(dz, dz));
}

static __device__ __forceinline__ unsigned long long u64max(unsigned long long a,
                                                            unsigned long long b) {
    return a > b ? a : b;
}

// f32 -> bf16 bits, round-to-nearest-even (finite inputs)
static __device__ __forceinline__ ushort f2bf(float f) {
    unsigned x = __float_as_uint(f);
    unsigned r = x + 0x7FFFu + ((x >> 16) & 1u);
    return (ushort)(r >> 16);
}

// Wave-wide u64 max via DPP (VALU pipe, no LDS) — r14-validated on HW.
template <int CTRL>
static __device__ __forceinline__ void dpp_max_level(int& lo, int& hi) {
    int olo = __builtin_amdgcn_update_dpp(lo, lo, CTRL, 0xF, 0xF, false);
    int ohi = __builtin_amdgcn_update_dpp(hi, hi, CTRL, 0xF, 0xF, false);
    unsigned long long o = ((unsigned long long)(unsigned)ohi << 32) | (unsigned)olo;
    unsigned long long k = ((unsigned long long)(unsigned)hi << 32) | (unsigned)lo;
    if (o > k) { lo = olo; hi = ohi; }
}

static __device__ __forceinline__ unsigned long long wave_max_u64(unsigned long long key) {
    int lo = (int)(unsigned)(key & 0xFFFFFFFFull);
    int hi = (int)(unsigned)(key >> 32);
    dpp_max_level<0x111>(lo, hi);   // row_shr:1
    dpp_max_level<0x112>(lo, hi);   // row_shr:2
    dpp_max_level<0x114>(lo, hi);   // row_shr:4
    dpp_max_level<0x118>(lo, hi);   // row_shr:8
    dpp_max_level<0x142>(lo, hi);   // row_bcast:15
    dpp_max_level<0x143>(lo, hi);   // row_bcast:31
    unsigned flo = (unsigned)__builtin_amdgcn_readlane(lo, 63);
    unsigned fhi = (unsigned)__builtin_amdgcn_readlane(hi, 63);
    return ((unsigned long long)fhi << 32) | flo;
}

// ---------------- Kernel: farthest point sampling (r14/r17 text, 624us) -----
__global__ __launch_bounds__(256) void k_fps(const float* __restrict__ xyz,
                                             float* __restrict__ out_xyz) {
    __shared__ __align__(16) float xs[Nn], ys[Nn], zs[Nn];
    __shared__ __align__(16) unsigned long long gbuf[2][4];
    const int b = blockIdx.x;
    const int tid = threadIdx.x;
    const int wid = tid >> 6, lane = tid & 63;
    const float* base = xyz + (size_t)b * 3 * Nn;
    for (int i = tid; i < Nn; i += 256) {
        xs[i] = base[i];
        ys[i] = base[Nn + i];
        zs[i] = base[2 * Nn + i];
    }
    __syncthreads();
    float px[16], py[16], pz[16], dist[16];
#pragma unroll
    for (int j = 0; j < 16; ++j) {
        int p = tid + j * 256;
        px[j] = xs[p]; py[j] = ys[p]; pz[j] = zs[p];
        dist[j] = 3.402823466e+38f;   // FLT_MAX, matches jnp.finfo(f32).max
    }
    int last = 0;
    if (tid == 0) {
        out_xyz[(size_t)(b * Sn) * 3 + 0] = xs[0];
        out_xyz[(size_t)(b * Sn) * 3 + 1] = ys[0];
        out_xyz[(size_t)(b * Sn) * 3 + 2] = zs[0];
    }
    for (int s = 1; s < Sn; ++s) {
        const float cx = xs[last], cy = ys[last], cz = zs[last];
        float mv = -1.0f; int mi = 0;
#pragma unroll
        for (int j = 0; j < 16; ++j) {
            float d = sqdist(px[j], py[j], pz[j], cx, cy, cz);
            float nd = fminf(dist[j], d);
            dist[j] = nd;
            if (nd > mv) { mv = nd; mi = tid + j * 256; }  // strict >: first-max wins
        }
        unsigned long long key =
            ((unsigned long long)__float_as_uint(mv) << 32) | (unsigned)(Nn - 1 - mi);
        key = wave_max_u64(key);            // all lanes hold wave max
        if (lane == 0) gbuf[s & 1][wid] = key;
        __syncthreads();
        const ulonglong2 g0 = *(const ulonglong2*)&gbuf[s & 1][0];
        const ulonglong2 g1 = *(const ulonglong2*)&gbuf[s & 1][2];
        key = u64max(u64max(g0.x, g0.y), u64max(g1.x, g1.y));
        const int nl = Nn - 1 - (int)(unsigned)(key & 0xFFFFFFFFull);
        if (tid == 0) {
            out_xyz[(size_t)(b * Sn + s) * 3 + 0] = xs[nl];
            out_xyz[(size_t)(b * Sn + s) * 3 + 1] = ys[nl];
            out_xyz[(size_t)(b * Sn + s) * 3 + 2] = zs[nl];
        }
        last = nl;
        // double-buffered gbuf: no second barrier (validated r9-r17)
    }
}

// ---- Wave-local ball query (validated r10-r17 ballot logic) ----------------
static __device__ __forceinline__ void wave_ball(const float* __restrict__ base,
                                                 float cx, float cy, float cz,
                                                 int lane, int* bslot) {
    int cnt = 0;
    int idx0 = -1;
    for (int chunk = 0; chunk < Nn / 64; ++chunk) {
        const int p = chunk * 64 + lane;
        const float d2 = sqdist(base[p], base[Nn + p], base[2 * Nn + p], cx, cy, cz);
        const bool in = (d2 <= 0.04f);             // f32(0.2*0.2)
        const unsigned long long m = __ballot(in);
        if (m != 0ull) {
            if (idx0 < 0) idx0 = chunk * 64 + __builtin_ctzll(m);
            const int rank = cnt + __popcll(m & ((1ull << lane) - 1ull));
            if (in && rank < Kn)
                bslot[rank] = p;                    // ascending by construction
            cnt += __popcll(m);
            if (cnt >= Kn) break;                   // wave-uniform
        }
    }
    if (lane < Kn && lane >= cnt)                   // pad with first index
        bslot[lane] = idx0;
}

// ---- Fused ball + bf16-MFMA conv + BN + ReLU + maxK ------------------------
// Block: 512 thr = 8 waves = 8 centers. D[64=(c,k)][256 o] = A[64][128]·W^T.
// A staged once in LDS (bf16, stride 136 ush); W staged per-32-f chunk
// ([o][f_local] bf16, stride 40 ush), prefetched one chunk ahead.
// Wave w: m-tile mt=w&3 (centers 2mt,2mt+1), o-half (w>>2)*128, 8 n-tiles.
// Fragments (mfma_f32_16x16x32_bf16): A/B lane l: 8 consecutive k at
// (l>>4)*8, row/col = l&15; D: col=l&15, row=(l>>4)*4+reg (m89-verified).
// Epilogue: literal bias->BN->ReLU per (k,o), then max over k (in-lane max4
// + shfl_xor(16)). bf16 rounding error ~0.01-0.04 << 0.17375 threshold.
__global__ __launch_bounds__(512) void k_feat(const float* __restrict__ xyz,
                                              const float* __restrict__ out_xyz,
                                              const float* __restrict__ feat,
                                              const float* __restrict__ conv_w,
                                              const float* __restrict__ conv_b,
                                              const float* __restrict__ bn_g,
                                              const float* __restrict__ bn_b,
                                              const float* __restrict__ bn_m,
                                              const float* __restrict__ bn_v,
                                              float* __restrict__ out_feat) {
    __shared__ __align__(16) ushort A_lds[64][136];   // [(c,k)][f] 17.4 KB
    __shared__ __align__(16) ushort Wc[COUTn][40];    // [o][f_local] 20.5 KB
    __shared__ int bidx[8][Kn];
    const int tid = threadIdx.x;
    const int wave = tid >> 6, lane = tid & 63;
    const int b  = blockIdx.x & 15;                 // XCD-grouped batches
    const int c0 = (blockIdx.x >> 4) * 8;
    const int bs = b * Sn + c0 + wave;

    // ball query (wave-local)
    const float* base = xyz + (size_t)b * 3 * Nn;
    const float cx = out_xyz[(size_t)bs * 3 + 0];
    const float cy = out_xyz[(size_t)bs * 3 + 1];
    const float cz = out_xyz[(size_t)bs * 3 + 2];
    wave_ball(base, cx, cy, cz, lane, &bidx[wave][0]);
    __syncthreads();   // bidx visible to all waves (A staging reads it)

    // stage A (once): thread: row r=tid>>3 (=(c<<3)|k), f-range (tid&7)*16..+15
    const float* fb = feat + (size_t)b * CINn * Nn;
    {
        const int r = tid >> 3, fo = tid & 7;
        const int pt = bidx[r >> 3][r & 7];
        ushort us[16];
#pragma unroll
        for (int i = 0; i < 16; ++i)
            us[i] = f2bf(fb[(size_t)(fo * 16 + i) * Nn + pt]);
        *(ushort8*)&A_lds[r][fo * 16]     = *(const ushort8*)&us[0];
        *(ushort8*)&A_lds[r][fo * 16 + 8] = *(const ushort8*)&us[8];
    }

    // W chunk prefetch (ks=0): thread: o=tid>>1, f-half (tid&1)*16
    const int wo = tid >> 1, wfh = tid & 1;
    float4 stgW[4];
    {
        const float4* src = (const float4*)(conv_w + (size_t)wo * CINn + wfh * 16);
#pragma unroll
        for (int i = 0; i < 4; ++i) stgW[i] = src[i];
    }

    const int mt = wave & 3;
    const int obase = (wave >> 2) * 128;
    f32x4 acc[8];
#pragma unroll
    for (int t = 0; t < 8; ++t) acc[t] = (f32x4){0.f, 0.f, 0.f, 0.f};

    const int arow = mt * 16 + (lane & 15);
    const int kgrp = (lane >> 4) * 8;

#pragma unroll
    for (int ks = 0; ks < 4; ++ks) {
        // park W chunk (16 bf16 per thread -> 2 b128 writes)
        {
            ushort us[16];
#pragma unroll
            for (int i = 0; i < 4; ++i) {
                us[i * 4 + 0] = f2bf(stgW[i].x);
                us[i * 4 + 1] = f2bf(stgW[i].y);
                us[i * 4 + 2] = f2bf(stgW[i].z);
                us[i * 4 + 3] = f2bf(stgW[i].w);
            }
            *(ushort8*)&Wc[wo][wfh * 16]     = *(const ushort8*)&us[0];
            *(ushort8*)&Wc[wo][wfh * 16 + 8] = *(const ushort8*)&us[8];
        }
        __syncthreads();   // Wc[ks] ready (iter 0: A_lds too)
        // prefetch next W chunk
        if (ks < 3) {
            const float4* src = (const float4*)(conv_w + (size_t)wo * CINn +
                                                (ks + 1) * 32 + wfh * 16);
#pragma unroll
            for (int i = 0; i < 4; ++i) stgW[i] = src[i];
        }
        // compute: one A-frag (reused), 8 n-tiles
        const bf16x8 a = *(const bf16x8*)&A_lds[arow][ks * 32 + kgrp];
#pragma unroll
        for (int t = 0; t < 8; ++t) {
            const int o = obase + t * 16 + (lane & 15);
            const bf16x8 bb = *(const bf16x8*)&Wc[o][kgrp];
            acc[t] = __builtin_amdgcn_mfma_f32_16x16x32_bf16(a, bb, acc[t], 0, 0, 0);
        }
        __syncthreads();   // compute done before Wc overwrite
    }

    // epilogue: literal bias+BN+ReLU per (k,o), then max over k.
    // Lane holds D rows (lane>>4)*4+i at col lane&15; rows 0-7 = center 2mt,
    // rows 8-15 = center 2mt+1. In-lane max over 4 rows (same center), then
    // shfl_xor(16) merges the two k-halves of each center.
    const int half = lane >> 4;                 // 0,1: center A; 2,3: center B
#pragma unroll
    for (int t = 0; t < 8; ++t) {
        const int o = obase + t * 16 + (lane & 15);
        const float bias = conv_b[o];
        const float g = bn_g[o], be = bn_b[o], mn = bn_m[o], vr = bn_v[o];
        const float inv = sqrtf(vr + 1e-5f);
        float m4 = -3.402823466e+38f;
#pragma unroll
        for (int i = 0; i < 4; ++i) {
            float z = acc[t][i] + bias;
            float y = g * (z - mn) / inv + be;
            y = fmaxf(y, 0.0f);                 // ReLU before max, literal order
            m4 = fmaxf(m4, y);
        }
        const float mo = __shfl_xor(m4, 16);    // merge k 0-3 with k 4-7
        const float mx = fmaxf(m4, mo);
        if (half == 0)
            out_feat[(size_t)(b * Sn + c0 + mt * 2) * COUTn + o] = mx;
        else if (half == 2)
            out_feat[(size_t)(b * Sn + c0 + mt * 2 + 1) * COUTn + o] = mx;
    }
}

extern "C" void kernel_launch(void* const* d_in, const int* in_sizes, int n_in,
                              void* d_out, int out_size, void* d_ws, size_t ws_size,
                              hipStream_t stream) {
    const float* xyz    = (const float*)d_in[0];
    const float* feat   = (const float*)d_in[1];
    const float* conv_w = (const float*)d_in[2];
    const float* conv_b = (const float*)d_in[3];
    const float* bn_g   = (const float*)d_in[4];
    const float* bn_b   = (const float*)d_in[5];
    const float* bn_m   = (const float*)d_in[6];
    const float* bn_v   = (const float*)d_in[7];

    float* out_xyz  = (float*)d_out;
    float* out_feat = out_xyz + (size_t)Bn * Sn * 3;

    // no workspace usage
    k_fps <<<dim3(Bn),           dim3(256), 0, stream>>>(xyz, out_xyz);
    k_feat<<<dim3(Bn * Sn / 8),  dim3(512), 0, stream>>>(xyz, out_xyz, feat,
                                                         conv_w, conv_b,
                                                         bn_g, bn_b, bn_m, bn_v,
                                                         out_feat);
}